// Round 18
// baseline (159.007 us; speedup 1.0000x reference)
//
#include <hip/hip_runtime.h>

#define L_SEQ 2688
#define DIM   1536
#define NH    12
#define HD    128
#define BLK_TOK 1344   // 3*H*W
#define HW_   448      // H*W
#define W_    28
#define NKIT  24       // DIM/64 K-iterations

typedef unsigned short u16;
typedef unsigned int   u32;
typedef __attribute__((ext_vector_type(4))) float f32x4;
typedef __attribute__((ext_vector_type(16))) float f32x16;
typedef __attribute__((ext_vector_type(8))) short s16x8;
typedef __attribute__((ext_vector_type(2))) int i32x2;
typedef __attribute__((ext_vector_type(4))) u32 u32x4;

__device__ __forceinline__ u16 f2b(float f) {
    u32 u = __builtin_bit_cast(u32, f);
    return (u16)((u + 0x7FFFu + ((u >> 16) & 1u)) >> 16);   // RNE
}
__device__ __forceinline__ float b2f(u16 b) {
    return __builtin_bit_cast(float, (u32)b << 16);
}
__device__ __forceinline__ u32 cvt_pk_bf16(float lo, float hi) {
    u32 r;
    asm("v_cvt_pk_bf16_f32 %0, %1, %2" : "=v"(r) : "v"(lo), "v"(hi));
    return r;
}

// -------------------- fused prep: x->bf16 (blocks 0..2015) ∥ W transpose
__global__ __launch_bounds__(256) void k_prep(const float* __restrict__ x,
                                              u16* __restrict__ xb,
                                              const float* __restrict__ w0,
                                              const float* __restrict__ w1,
                                              const float* __restrict__ w2,
                                              const float* __restrict__ w3,
                                              u16* __restrict__ wt_all) {
    __shared__ float t[64][65];
    const int bid = blockIdx.x;
    if (bid < 2016) {
        const int n4 = (int)((size_t)L_SEQ * DIM / 4);
        int i = bid * 256 + threadIdx.x;
        const int stride = 2016 * 256;
        for (; i < n4; i += stride) {
            float4 v = ((const float4*)x)[i];
            ushort4 o;
            o.x = f2b(v.x); o.y = f2b(v.y); o.z = f2b(v.z); o.w = f2b(v.w);
            ((ushort4*)xb)[i] = o;
        }
    } else {
        const int idx = bid - 2016;               // 0..2303
        const int z = idx / 576;
        const int rem = idx - z * 576;
        const int by = rem / 24, bx = rem - by * 24;
        const float* w = z == 0 ? w0 : z == 1 ? w1 : z == 2 ? w2 : w3;
        u16* wt = wt_all + (size_t)z * DIM * DIM;
        const int k0 = by * 64, n0 = bx * 64;
        const int c = threadIdx.x & 63, rg = threadIdx.x >> 6;
#pragma unroll
        for (int it = 0; it < 16; ++it) {
            int r = rg * 16 + it;
            t[r][c] = w[(size_t)(k0 + r) * DIM + n0 + c];
        }
        __syncthreads();
#pragma unroll
        for (int it = 0; it < 16; ++it) {
            int r = rg * 16 + it;
            wt[(size_t)(n0 + r) * DIM + k0 + c] = f2b(t[c][r]);
        }
    }
}

// --------------------------------- GEMM v4: single-buffered 32 KB LDS tile
// 128x128 tile, BK=64, 4 waves, 32x32x16 MFMA, row-major granule-XOR LDS.
// Single buffer -> 4 blocks/CU (all 756 co-resident, 16 waves/CU); the
// per-iter stage drain is covered by cross-block TLP.
template<int OUTF>
__global__ __launch_bounds__(256) void k_gemm(const u16* __restrict__ A,
                                              const u16* __restrict__ Bt_all,
                                              const float* __restrict__ b0,
                                              const float* __restrict__ b1,
                                              const float* __restrict__ b2,
                                              void* __restrict__ out_all) {
    // bijective XCD swizzle over flat worklist
    const int NW = OUTF ? 252 : 756;
    const int qc = NW >> 3, rq = NW & 7;
    const int xcd = blockIdx.x & 7, idx = blockIdx.x >> 3;
    const int work = (xcd < rq) ? xcd * (qc + 1) + idx
                                : rq * (qc + 1) + (xcd - rq) * qc + idx;
    int z, bm, bn;
    if (OUTF) { z = 0; bm = work / 12; bn = work - bm * 12; }
    else      { z = work / 252; int rem = work - z * 252; bm = rem / 12; bn = rem - bm * 12; }

    const u16* Bt = Bt_all + (size_t)z * DIM * DIM;
    const float* bias = z == 0 ? b0 : z == 1 ? b1 : b2;

    __shared__ u16 lbuf[2][8192];   // [A/B][128 rows x 64 cols, granule-swizzled]
    const int tid = threadIdx.x, lane = tid & 63, wid = tid >> 6;
    const int wm = wid >> 1, wn = wid & 1;
    const int q31 = lane & 31, hi = lane >> 5;

    const int sr = tid >> 3, sc = tid & 7;
    const int scol = 8 * (sc ^ (sr & 7));
    const u16* aRow = A  + (size_t)(bm * 128 + sr) * DIM + scol;
    const u16* bRow = Bt + (size_t)(bn * 128 + sr) * DIM + scol;

#define GSTAGE(KT)                                                                 \
    {                                                                              \
        _Pragma("unroll")                                                          \
        for (int i = 0; i < 4; ++i)                                                \
            __builtin_amdgcn_global_load_lds(                                      \
                (const __attribute__((address_space(1))) u32*)(aRow + (size_t)i * 32 * DIM + (KT) * 64), \
                (__attribute__((address_space(3))) u32*)((char*)&lbuf[0][0] + i * 4096 + tid * 16), \
                16, 0, 0);                                                         \
        _Pragma("unroll")                                                          \
        for (int i = 0; i < 4; ++i)                                                \
            __builtin_amdgcn_global_load_lds(                                      \
                (const __attribute__((address_space(1))) u32*)(bRow + (size_t)i * 32 * DIM + (KT) * 64), \
                (__attribute__((address_space(3))) u32*)((char*)&lbuf[1][0] + i * 4096 + tid * 16), \
                16, 0, 0);                                                         \
    }

    f32x16 acc[2][2] = {};

    for (int kt = 0; kt < NKIT; ++kt) {
        GSTAGE(kt);
        __syncthreads();                 // drain staging (vmcnt0 + barrier)
        const char* bufA = (const char*)&lbuf[0][0];
        const char* bufB = (const char*)&lbuf[1][0];
        s16x8 af[2][4], bf[2][4];
#pragma unroll
        for (int f = 0; f < 2; ++f)
#pragma unroll
            for (int kk = 0; kk < 4; ++kk) {
                const int ra = wm * 64 + f * 32 + q31;
                const int rb = wn * 64 + f * 32 + q31;
                const int cg = kk * 2 + hi;
                af[f][kk] = *(const s16x8*)(bufA + ra * 128 + (((cg) ^ (q31 & 7)) << 4));
                bf[f][kk] = *(const s16x8*)(bufB + rb * 128 + (((cg) ^ (q31 & 7)) << 4));
            }
        __builtin_amdgcn_s_setprio(1);
#pragma unroll
        for (int kk = 0; kk < 4; ++kk)
#pragma unroll
            for (int fm = 0; fm < 2; ++fm)
#pragma unroll
                for (int fn = 0; fn < 2; ++fn)
                    acc[fm][fn] = __builtin_amdgcn_mfma_f32_32x32x16_bf16(af[fm][kk], bf[fn][kk], acc[fm][fn], 0, 0, 0);
        __builtin_amdgcn_s_setprio(0);
        __syncthreads();                 // readers done before next overwrite
    }

#pragma unroll
    for (int fn = 0; fn < 2; ++fn) {
        const int col = bn * 128 + wn * 64 + fn * 32 + q31;
        const float bv = bias[col];
#pragma unroll
        for (int fm = 0; fm < 2; ++fm) {
#pragma unroll
            for (int e = 0; e < 16; ++e) {
                const int row = bm * 128 + wm * 64 + fm * 32 + (e & 3) + 8 * (e >> 2) + 4 * hi;
                const float v = acc[fm][fn][e] + bv;
                if (OUTF)
                    ((float*)out_all)[(size_t)row * DIM + col] = v;
                else
                    ((u16*)out_all)[(size_t)z * L_SEQ * DIM + (size_t)row * DIM + col] = f2b(v);
            }
        }
    }
#undef GSTAGE
}

// --------- fused post: RMSNorm+RoPE (blocks 0..5375) ∥ V transpose (rest)
__global__ __launch_bounds__(256) void k_post(const u16* __restrict__ pre_all,
                                              const float* __restrict__ gq,
                                              const float* __restrict__ gk,
                                              const float* __restrict__ freqs,
                                              u16* __restrict__ qh,
                                              u16* __restrict__ kh,
                                              u16* __restrict__ vt) {
    __shared__ float sred[4];
    __shared__ u16 tt[64][68];
    const int bid = blockIdx.x;
    const int t = threadIdx.x;
    if (bid < 5376) {
        const int which = bid & 1;
        const int i = bid >> 1;
        const u16* pre = pre_all + (size_t)which * L_SEQ * DIM;
        const float* g = which ? gk : gq;
        u16* outh = which ? kh : qh;
        const u32* prow = (const u32*)(pre + (size_t)i * DIM);

        float re[3], im[3];
        float ss = 0.f;
#pragma unroll
        for (int a = 0; a < 3; ++a) {
            u32 p = prow[t + a * 256];
            float x = b2f((u16)(p & 0xFFFFu)), y = b2f((u16)(p >> 16));
            re[a] = x; im[a] = y;
            ss += x * x + y * y;
        }
#pragma unroll
        for (int o = 32; o > 0; o >>= 1) ss += __shfl_down(ss, o, 64);
        if ((t & 63) == 0) sred[t >> 6] = ss;
        __syncthreads();
        float rms = rsqrtf((sred[0] + sred[1] + sred[2] + sred[3]) * (1.0f / DIM) + 1e-6f);

        const int f = i / HW_;
        const int rem = i - f * HW_;
        const int hp = rem / W_;
        const int wp = rem - hp * W_;
#pragma unroll
        for (int a = 0; a < 3; ++a) {
            int j = t + a * 256;
            int h = j >> 6, pj = j & 63;
            float2 gg = ((const float2*)g)[j];
            float x = re[a] * rms * gg.x;
            float y = im[a] * rms * gg.y;
            int ridx = pj < 22 ? f : (pj < 43 ? hp : wp);
            float2 cs = ((const float2*)freqs)[ridx * 64 + pj];
            float ore = x * cs.x - y * cs.y;
            float oim = x * cs.y + y * cs.x;
            u32 o = (u32)f2b(ore) | ((u32)f2b(oim) << 16);
            ((u32*)outh)[(size_t)h * (L_SEQ * 64) + (size_t)i * 64 + pj] = o;
        }
    } else {
        const int idx = bid - 5376;               // 0..1007
        const int h = idx / 84;
        const int rem = idx - h * 84;
        const int d0 = (rem / 42) * 64, i0 = (rem % 42) * 64;
        const u16* vpre = pre_all + (size_t)2 * L_SEQ * DIM;
        const int c = t & 63, rg = t >> 6;
#pragma unroll
        for (int it = 0; it < 16; ++it) {
            int r = rg * 16 + it;
            tt[r][c] = vpre[(size_t)(i0 + r) * DIM + h * HD + d0 + c];
        }
        __syncthreads();
#pragma unroll
        for (int it = 0; it < 16; ++it) {
            int r = rg * 16 + it;  // d index
            vt[(size_t)h * (HD * L_SEQ) + (size_t)(d0 + r) * L_SEQ + i0 + c] = tt[c][r];
        }
    }
}

// ----------------------------------------------------- flash attention v17
// (unchanged from R17 — best measured: 69.5 us)
__global__ __launch_bounds__(256, 2) void k_attn(const u16* __restrict__ qh,
                                                 const u16* __restrict__ kh,
                                                 const u16* __restrict__ vt,
                                                 u16* __restrict__ ob) {
    __shared__ char lsm[2][32768];   // dbuf slots: [0,16K) K[64][128] swz, [16K,32K) V^T[128][64] swz

    // bijective XCD swizzle: 504 = 8*63; long/short interleaved within head
    const int flat = blockIdx.x;
    const int xcd = flat & 7, idx = flat >> 3;
    const int work = xcd * 63 + idx;
    const int head = work / 42;
    const int w2 = work - head * 42;
    const int qt = (w2 & 1) ? 21 + (w2 >> 1) : (w2 >> 1);
    const int nt = (qt < 21) ? 21 : 42;

    const int tid = threadIdx.x, lane = tid & 63, w = tid >> 6;
    const int pairI = w >> 1;        // j-half this wave computes
    const int qhalf = w & 1;         // q-row half of the 64-row job
    const int q31 = lane & 31, hi = lane >> 5;
    const size_t hOff = (size_t)head * ((size_t)L_SEQ * HD);
    const u16* Kh = kh + hOff;
    const u16* Vh = vt + hOff;
    const int qrow0 = qt * 64 + qhalf * 32;

    // Q B-fragments (n=q31, k = 16kk + 8hi .. +8): 8 k-steps
    s16x8 aq[8];
#pragma unroll
    for (int kk = 0; kk < 8; ++kk)
        aq[kk] = *(const s16x8*)&qh[hOff + (size_t)(qrow0 + q31) * HD + kk * 16 + hi * 8];

    // staging decomposition: ALL 256 threads stage the shared 32 KB tile.
    const int rh = tid >> 4, ck = tid & 15;
    const int rv = tid >> 3, cv = tid & 7;
    const int koff = 8 * (ck ^ rh);
    const int voff = 8 * (cv ^ (rv & 7));

#define STAGE_TILE(TG, BUF)                                                       \
    {                                                                             \
        char* dst = lsm[BUF];                                                     \
        _Pragma("unroll")                                                         \
        for (int i = 0; i < 4; ++i) {                                             \
            const u16* src = Kh + (size_t)((TG) * 64 + i * 16 + rh) * HD + koff;  \
            __builtin_amdgcn_global_load_lds(                                     \
                (const __attribute__((address_space(1))) u32*)src,                \
                (__attribute__((address_space(3))) u32*)(dst + i * 4096 + tid * 16), 16, 0, 0); \
        }                                                                         \
        _Pragma("unroll")                                                         \
        for (int i = 0; i < 4; ++i) {                                             \
            const u16* src = Vh + (size_t)(i * 32 + rv) * L_SEQ + (TG) * 64 + voff; \
            __builtin_amdgcn_global_load_lds(                                     \
                (const __attribute__((address_space(1))) u32*)src,                \
                (__attribute__((address_space(3))) u32*)(dst + 16384 + i * 4096 + tid * 16), 16, 0, 0); \
        }                                                                         \
    }

    f32x16 acc[4] = {};
    float mrun = -1e30f, lrun = 0.f;
    const float sc2 = 0.12751739646917983f;  // 1/sqrt(128) * log2(e)
    const int krow = pairI * 32 + q31;

    STAGE_TILE(0, 0);
    __syncthreads();
    for (int t = 0; t < nt; ++t) {
        if (t < nt - 1) STAGE_TILE(t + 1, (t + 1) & 1);
        const char* slot = lsm[t & 1];

        // ---- S^T = K Q^T, two independent accumulator chains (depth 4 each)
        f32x16 sv0 = {}, sv1 = {};
        __builtin_amdgcn_s_setprio(1);
#pragma unroll
        for (int kk = 0; kk < 4; ++kk) {
            int off0 = krow * 256 + ((kk * 32 + hi * 16) ^ ((q31 & 15) << 4));
            int off1 = krow * 256 + (((kk + 4) * 32 + hi * 16) ^ ((q31 & 15) << 4));
            s16x8 kf0 = *(const s16x8*)(slot + off0);
            s16x8 kf1 = *(const s16x8*)(slot + off1);
            sv0 = __builtin_amdgcn_mfma_f32_32x32x16_bf16(kf0, aq[kk], sv0, 0, 0, 0);
            sv1 = __builtin_amdgcn_mfma_f32_32x32x16_bf16(kf1, aq[kk + 4], sv1, 0, 0, 0);
        }
        __builtin_amdgcn_s_setprio(0);
        f32x16 sv;
#pragma unroll
        for (int e = 0; e < 16; ++e) sv[e] = sv0[e] + sv1[e];

        // ---- row max: depth-4 pairwise tree + one cross-half shuffle
        float m8[8];
#pragma unroll
        for (int e = 0; e < 8; ++e) m8[e] = fmaxf(sv[e], sv[e + 8]);
        float m4a = fmaxf(m8[0], m8[1]), m4b = fmaxf(m8[2], m8[3]);
        float m4c = fmaxf(m8[4], m8[5]), m4d = fmaxf(m8[6], m8[7]);
        float mx = fmaxf(fmaxf(m4a, m4b), fmaxf(m4c, m4d));
        mx = fmaxf(mx, __shfl_xor(mx, 32, 64));
        mx *= sc2;
        const int resc = (mx - mrun) > 11.5f;
        const float mm = resc ? mx : mrun;
        const float fac = resc ? __builtin_amdgcn_exp2f(mrun - mm) : 1.0f;
        mrun = mm;
#pragma unroll
        for (int e = 0; e < 16; ++e)
            sv[e] = __builtin_amdgcn_exp2f(sv[e] * sc2 - mm);
        float s8[8];
#pragma unroll
        for (int e = 0; e < 8; ++e) s8[e] = sv[e] + sv[e + 8];
        float s4a = s8[0] + s8[1], s4b = s8[2] + s8[3];
        float s4c = s8[4] + s8[5], s4d = s8[6] + s8[7];
        float sum = (s4a + s4b) + (s4c + s4d);
        sum += __shfl_xor(sum, 32, 64);
        lrun = lrun * fac + sum;
        if (__any(resc)) {
#pragma unroll
            for (int ds = 0; ds < 4; ++ds)
#pragma unroll
                for (int e = 0; e < 16; ++e) acc[ds][e] *= fac;
        }

        // ---- pack P -> 2 B-fragments in-register (cvt_pk + permlane32_swap)
        s16x8 pa[2];
#pragma unroll
        for (int hf = 0; hf < 2; ++hf) {
            u32 a0 = cvt_pk_bf16(sv[hf * 8 + 0], sv[hf * 8 + 1]);
            u32 a1 = cvt_pk_bf16(sv[hf * 8 + 2], sv[hf * 8 + 3]);
            u32 b0 = cvt_pk_bf16(sv[hf * 8 + 4], sv[hf * 8 + 5]);
            u32 b1 = cvt_pk_bf16(sv[hf * 8 + 6], sv[hf * 8 + 7]);
            i32x2 r0 = __builtin_amdgcn_permlane32_swap((int)a0, (int)b0, false, false);
            i32x2 r1 = __builtin_amdgcn_permlane32_swap((int)a1, (int)b1, false, false);
            u32x4 fw;
            fw.x = (u32)r0.x; fw.y = (u32)r1.x; fw.z = (u32)r0.y; fw.w = (u32)r1.y;
            pa[hf] = __builtin_bit_cast(s16x8, fw);
        }

        // ---- O^T += V^T P^T over this pair's j-half (2 k-steps of 16)
        __builtin_amdgcn_s_setprio(1);
#pragma unroll
        for (int jstep = 0; jstep < 2; ++jstep)
#pragma unroll
            for (int ds = 0; ds < 4; ++ds) {
                int off = 16384 + (ds * 32 + q31) * 128 +
                          ((pairI * 64 + jstep * 32 + hi * 16) ^ ((q31 & 7) << 4));
                s16x8 vf = *(const s16x8*)(slot + off);
                acc[ds] = __builtin_amdgcn_mfma_f32_32x32x16_bf16(vf, pa[jstep], acc[ds], 0, 0, 0);
            }
        __builtin_amdgcn_s_setprio(0);
        __syncthreads();                 // readers done + next stage drained
    }

    // ---- pair merge in LDS: waves 2,3 publish; waves 0,1 combine + output
    float2* mlb = (float2*)(lsm[1]);
    char* accb = lsm[0];
    if (w >= 2) {
        char* base = accb + qhalf * 16384 + lane * 256;
#pragma unroll
        for (int ds = 0; ds < 4; ++ds)
#pragma unroll
            for (int g = 0; g < 4; ++g) {
                f32x4 v4;
#pragma unroll
                for (int e = 0; e < 4; ++e) v4[e] = acc[ds][g * 4 + e];
                *(f32x4*)(base + (((ds * 4 + g) * 16) ^ ((lane & 15) << 4))) = v4;
            }
        if (hi == 0) {
            float2 t2; t2.x = mrun; t2.y = lrun;
            mlb[qhalf * 32 + q31] = t2;
        }
    }
    __syncthreads();
    if (w < 2) {
        float2 ml2 = mlb[qhalf * 32 + q31];
        float M = fmaxf(mrun, ml2.x);
        float wa = exp2f(mrun - M), wb = exp2f(ml2.x - M);
        lrun = lrun * wa + ml2.y * wb;
        const char* base = accb + qhalf * 16384 + lane * 256;
#pragma unroll
        for (int ds = 0; ds < 4; ++ds)
#pragma unroll
            for (int g = 0; g < 4; ++g) {
                f32x4 v4 = *(const f32x4*)(base + (((ds * 4 + g) * 16) ^ ((lane & 15) << 4)));
#pragma unroll
                for (int e = 0; e < 4; ++e) acc[ds][g * 4 + e] = acc[ds][g * 4 + e] * wa + v4[e] * wb;
            }
        const float inv = 1.0f / lrun;
        u16* orow = ob + (size_t)(qrow0 + q31) * DIM + head * HD;
#pragma unroll
        for (int ds = 0; ds < 4; ++ds)
#pragma unroll
            for (int g = 0; g < 4; ++g) {
                uint2 pk2;
                pk2.x = cvt_pk_bf16(acc[ds][g * 4 + 0] * inv, acc[ds][g * 4 + 1] * inv);
                pk2.y = cvt_pk_bf16(acc[ds][g * 4 + 2] * inv, acc[ds][g * 4 + 3] * inv);
                *(uint2*)(orow + ds * 32 + g * 8 + hi * 4) = pk2;
            }
    }
#undef STAGE_TILE
}

// ---------------------------------------------------------------- launcher
extern "C" void kernel_launch(void* const* d_in, const int* in_sizes, int n_in,
                              void* d_out, int out_size, void* d_ws, size_t ws_size,
                              hipStream_t stream) {
    const float* x     = (const float*)d_in[0];
    const float* freqs = (const float*)d_in[3];
    const float* Wq    = (const float*)d_in[4];
    const float* bq    = (const float*)d_in[5];
    const float* Wk    = (const float*)d_in[6];
    const float* bk    = (const float*)d_in[7];
    const float* Wv    = (const float*)d_in[8];
    const float* bv    = (const float*)d_in[9];
    const float* Wo    = (const float*)d_in[10];
    const float* bo    = (const float*)d_in[11];
    const float* gq    = (const float*)d_in[12];
    const float* gk    = (const float*)d_in[13];

    const size_t LD = (size_t)L_SEQ * DIM;   // elements
    u16* wt_all  = (u16*)d_ws;                         // 4 * DIM*DIM bf16
    u16* xb      = wt_all + (size_t)4 * DIM * DIM;     // L*DIM
    u16* pre_all = xb + LD;                            // 3 * L*DIM (q,k,v pre)
    u16* qh      = pre_all + 3 * LD;                   // [h][i][d]
    u16* kh2     = qh + LD;
    u16* vt      = kh2 + LD;
    u16* ob      = vt + LD;                            // attn out bf16 [i][c]

    k_prep<<<dim3(2016 + 2304), 256, 0, stream>>>(x, xb, Wq, Wk, Wv, Wo, wt_all);
    k_gemm<0><<<dim3(756), 256, 0, stream>>>(xb, wt_all, bq, bk, bv, pre_all);
    k_post<<<dim3(5376 + 1008), 256, 0, stream>>>(pre_all, gq, gk, freqs, qh, kh2, vt);
    k_attn<<<dim3(504), 256, 0, stream>>>(qh, kh2, vt, ob);
    k_gemm<1><<<dim3(252), 256, 0, stream>>>(ob, wt_all + (size_t)3 * DIM * DIM, bo, bo, bo, d_out);
}

// Round 19
// 154.918 us; speedup vs baseline: 1.0264x; 1.0264x over previous
//
#include <hip/hip_runtime.h>

#define L_SEQ 2688
#define DIM   1536
#define NH    12
#define HD    128
#define BLK_TOK 1344   // 3*H*W
#define HW_   448      // H*W
#define W_    28
#define NKIT  24       // DIM/64 K-iterations

typedef unsigned short u16;
typedef unsigned int   u32;
typedef __attribute__((ext_vector_type(4))) float f32x4;
typedef __attribute__((ext_vector_type(16))) float f32x16;
typedef __attribute__((ext_vector_type(8))) short s16x8;
typedef __attribute__((ext_vector_type(2))) int i32x2;
typedef __attribute__((ext_vector_type(4))) u32 u32x4;

__device__ __forceinline__ u16 f2b(float f) {
    u32 u = __builtin_bit_cast(u32, f);
    return (u16)((u + 0x7FFFu + ((u >> 16) & 1u)) >> 16);   // RNE
}
__device__ __forceinline__ float b2f(u16 b) {
    return __builtin_bit_cast(float, (u32)b << 16);
}
__device__ __forceinline__ u32 cvt_pk_bf16(float lo, float hi) {
    u32 r;
    asm("v_cvt_pk_bf16_f32 %0, %1, %2" : "=v"(r) : "v"(lo), "v"(hi));
    return r;
}

// -------------------- fused prep: x->bf16 (blocks 0..2015) ∥ W transpose
__global__ __launch_bounds__(256) void k_prep(const float* __restrict__ x,
                                              u16* __restrict__ xb,
                                              const float* __restrict__ w0,
                                              const float* __restrict__ w1,
                                              const float* __restrict__ w2,
                                              const float* __restrict__ w3,
                                              u16* __restrict__ wt_all) {
    __shared__ float t[64][65];
    const int bid = blockIdx.x;
    if (bid < 2016) {
        const int n4 = (int)((size_t)L_SEQ * DIM / 4);
        int i = bid * 256 + threadIdx.x;
        const int stride = 2016 * 256;
        for (; i < n4; i += stride) {
            float4 v = ((const float4*)x)[i];
            ushort4 o;
            o.x = f2b(v.x); o.y = f2b(v.y); o.z = f2b(v.z); o.w = f2b(v.w);
            ((ushort4*)xb)[i] = o;
        }
    } else {
        const int idx = bid - 2016;               // 0..2303
        const int z = idx / 576;
        const int rem = idx - z * 576;
        const int by = rem / 24, bx = rem - by * 24;
        const float* w = z == 0 ? w0 : z == 1 ? w1 : z == 2 ? w2 : w3;
        u16* wt = wt_all + (size_t)z * DIM * DIM;
        const int k0 = by * 64, n0 = bx * 64;
        const int c = threadIdx.x & 63, rg = threadIdx.x >> 6;
#pragma unroll
        for (int it = 0; it < 16; ++it) {
            int r = rg * 16 + it;
            t[r][c] = w[(size_t)(k0 + r) * DIM + n0 + c];
        }
        __syncthreads();
#pragma unroll
        for (int it = 0; it < 16; ++it) {
            int r = rg * 16 + it;
            wt[(size_t)(n0 + r) * DIM + k0 + c] = f2b(t[c][r]);
        }
    }
}

// ---------------- GEMM v5: dbuf + COUNTED vmcnt pipeline (T4), raw barriers
// 128x128 tile, BK=64, 4 waves, 32x32x16 MFMA, row-major granule-XOR LDS.
// Stage(kt) waited with vmcnt(8) while stage(kt+1)'s 8 loads stay in flight
// across the barrier; stage(kt+2) issued after the readers-done barrier.
template<int OUTF>
__global__ __launch_bounds__(256) void k_gemm(const u16* __restrict__ A,
                                              const u16* __restrict__ Bt_all,
                                              const float* __restrict__ b0,
                                              const float* __restrict__ b1,
                                              const float* __restrict__ b2,
                                              void* __restrict__ out_all) {
    // bijective XCD swizzle over flat worklist
    const int NW = OUTF ? 252 : 756;
    const int qc = NW >> 3, rq = NW & 7;
    const int xcd = blockIdx.x & 7, idx = blockIdx.x >> 3;
    const int work = (xcd < rq) ? xcd * (qc + 1) + idx
                                : rq * (qc + 1) + (xcd - rq) * qc + idx;
    int z, bm, bn;
    if (OUTF) { z = 0; bm = work / 12; bn = work - bm * 12; }
    else      { z = work / 252; int rem = work - z * 252; bm = rem / 12; bn = rem - bm * 12; }

    const u16* Bt = Bt_all + (size_t)z * DIM * DIM;
    const float* bias = z == 0 ? b0 : z == 1 ? b1 : b2;

    __shared__ u16 lbuf[2][2][8192];   // [dbuf][A/B][128 rows x 64 cols, granule-swizzled]
    const int tid = threadIdx.x, lane = tid & 63, wid = tid >> 6;
    const int wm = wid >> 1, wn = wid & 1;
    const int q31 = lane & 31, hi = lane >> 5;

    const int sr = tid >> 3, sc = tid & 7;
    const int scol = 8 * (sc ^ (sr & 7));
    const u16* aRow = A  + (size_t)(bm * 128 + sr) * DIM + scol;
    const u16* bRow = Bt + (size_t)(bn * 128 + sr) * DIM + scol;

#define GSTAGE(KT, BUF)                                                            \
    {                                                                              \
        _Pragma("unroll")                                                          \
        for (int i = 0; i < 4; ++i)                                                \
            __builtin_amdgcn_global_load_lds(                                      \
                (const __attribute__((address_space(1))) u32*)(aRow + (size_t)i * 32 * DIM + (KT) * 64), \
                (__attribute__((address_space(3))) u32*)((char*)&lbuf[BUF][0][0] + i * 4096 + tid * 16), \
                16, 0, 0);                                                         \
        _Pragma("unroll")                                                          \
        for (int i = 0; i < 4; ++i)                                                \
            __builtin_amdgcn_global_load_lds(                                      \
                (const __attribute__((address_space(1))) u32*)(bRow + (size_t)i * 32 * DIM + (KT) * 64), \
                (__attribute__((address_space(3))) u32*)((char*)&lbuf[BUF][1][0] + i * 4096 + tid * 16), \
                16, 0, 0);                                                         \
    }

    f32x16 acc[2][2] = {};

    GSTAGE(0, 0);
    GSTAGE(1, 1);
    for (int kt = 0; kt < NKIT; ++kt) {
        // wait stage kt only; stage kt+1 (8 loads) stays in flight
        if (kt < NKIT - 1)
            asm volatile("s_waitcnt vmcnt(8)" ::: "memory");
        else
            asm volatile("s_waitcnt vmcnt(0)" ::: "memory");
        __builtin_amdgcn_s_barrier();
        __builtin_amdgcn_sched_barrier(0);

        const char* bufA = (const char*)&lbuf[kt & 1][0][0];
        const char* bufB = (const char*)&lbuf[kt & 1][1][0];
        s16x8 af[2][4], bf[2][4];
#pragma unroll
        for (int f = 0; f < 2; ++f)
#pragma unroll
            for (int kk = 0; kk < 4; ++kk) {
                const int ra = wm * 64 + f * 32 + q31;
                const int rb = wn * 64 + f * 32 + q31;
                const int cg = kk * 2 + hi;
                af[f][kk] = *(const s16x8*)(bufA + ra * 128 + (((cg) ^ (q31 & 7)) << 4));
                bf[f][kk] = *(const s16x8*)(bufB + rb * 128 + (((cg) ^ (q31 & 7)) << 4));
            }
        __builtin_amdgcn_s_setprio(1);
#pragma unroll
        for (int kk = 0; kk < 4; ++kk)
#pragma unroll
            for (int fm = 0; fm < 2; ++fm)
#pragma unroll
                for (int fn = 0; fn < 2; ++fn)
                    acc[fm][fn] = __builtin_amdgcn_mfma_f32_32x32x16_bf16(af[fm][kk], bf[fn][kk], acc[fm][fn], 0, 0, 0);
        __builtin_amdgcn_s_setprio(0);
        // all ds_read results consumed by MFMAs above (lgkmcnt drained by
        // data dependence) -> safe to signal readers-done without waitcnt
        __builtin_amdgcn_sched_barrier(0);
        __builtin_amdgcn_s_barrier();
        __builtin_amdgcn_sched_barrier(0);
        if (kt + 2 < NKIT) GSTAGE(kt + 2, kt & 1);
    }

#pragma unroll
    for (int fn = 0; fn < 2; ++fn) {
        const int col = bn * 128 + wn * 64 + fn * 32 + q31;
        const float bv = bias[col];
#pragma unroll
        for (int fm = 0; fm < 2; ++fm) {
#pragma unroll
            for (int e = 0; e < 16; ++e) {
                const int row = bm * 128 + wm * 64 + fm * 32 + (e & 3) + 8 * (e >> 2) + 4 * hi;
                const float v = acc[fm][fn][e] + bv;
                if (OUTF)
                    ((float*)out_all)[(size_t)row * DIM + col] = v;
                else
                    ((u16*)out_all)[(size_t)z * L_SEQ * DIM + (size_t)row * DIM + col] = f2b(v);
            }
        }
    }
#undef GSTAGE
}

// --------- fused post: RMSNorm+RoPE (blocks 0..5375) ∥ V transpose (rest)
__global__ __launch_bounds__(256) void k_post(const u16* __restrict__ pre_all,
                                              const float* __restrict__ gq,
                                              const float* __restrict__ gk,
                                              const float* __restrict__ freqs,
                                              u16* __restrict__ qh,
                                              u16* __restrict__ kh,
                                              u16* __restrict__ vt) {
    __shared__ float sred[4];
    __shared__ u16 tt[64][68];
    const int bid = blockIdx.x;
    const int t = threadIdx.x;
    if (bid < 5376) {
        const int which = bid & 1;
        const int i = bid >> 1;
        const u16* pre = pre_all + (size_t)which * L_SEQ * DIM;
        const float* g = which ? gk : gq;
        u16* outh = which ? kh : qh;
        const u32* prow = (const u32*)(pre + (size_t)i * DIM);

        float re[3], im[3];
        float ss = 0.f;
#pragma unroll
        for (int a = 0; a < 3; ++a) {
            u32 p = prow[t + a * 256];
            float x = b2f((u16)(p & 0xFFFFu)), y = b2f((u16)(p >> 16));
            re[a] = x; im[a] = y;
            ss += x * x + y * y;
        }
#pragma unroll
        for (int o = 32; o > 0; o >>= 1) ss += __shfl_down(ss, o, 64);
        if ((t & 63) == 0) sred[t >> 6] = ss;
        __syncthreads();
        float rms = rsqrtf((sred[0] + sred[1] + sred[2] + sred[3]) * (1.0f / DIM) + 1e-6f);

        const int f = i / HW_;
        const int rem = i - f * HW_;
        const int hp = rem / W_;
        const int wp = rem - hp * W_;
#pragma unroll
        for (int a = 0; a < 3; ++a) {
            int j = t + a * 256;
            int h = j >> 6, pj = j & 63;
            float2 gg = ((const float2*)g)[j];
            float x = re[a] * rms * gg.x;
            float y = im[a] * rms * gg.y;
            int ridx = pj < 22 ? f : (pj < 43 ? hp : wp);
            float2 cs = ((const float2*)freqs)[ridx * 64 + pj];
            float ore = x * cs.x - y * cs.y;
            float oim = x * cs.y + y * cs.x;
            u32 o = (u32)f2b(ore) | ((u32)f2b(oim) << 16);
            ((u32*)outh)[(size_t)h * (L_SEQ * 64) + (size_t)i * 64 + pj] = o;
        }
    } else {
        const int idx = bid - 5376;               // 0..1007
        const int h = idx / 84;
        const int rem = idx - h * 84;
        const int d0 = (rem / 42) * 64, i0 = (rem % 42) * 64;
        const u16* vpre = pre_all + (size_t)2 * L_SEQ * DIM;
        const int c = t & 63, rg = t >> 6;
#pragma unroll
        for (int it = 0; it < 16; ++it) {
            int r = rg * 16 + it;
            tt[r][c] = vpre[(size_t)(i0 + r) * DIM + h * HD + d0 + c];
        }
        __syncthreads();
#pragma unroll
        for (int it = 0; it < 16; ++it) {
            int r = rg * 16 + it;  // d index
            vt[(size_t)h * (HD * L_SEQ) + (size_t)(d0 + r) * L_SEQ + i0 + c] = tt[c][r];
        }
    }
}

// ----------------------------------------------------- flash attention v17
// (unchanged from R17 — best measured: 69.5 us)
__global__ __launch_bounds__(256, 2) void k_attn(const u16* __restrict__ qh,
                                                 const u16* __restrict__ kh,
                                                 const u16* __restrict__ vt,
                                                 u16* __restrict__ ob) {
    __shared__ char lsm[2][32768];   // dbuf slots: [0,16K) K[64][128] swz, [16K,32K) V^T[128][64] swz

    // bijective XCD swizzle: 504 = 8*63; long/short interleaved within head
    const int flat = blockIdx.x;
    const int xcd = flat & 7, idx = flat >> 3;
    const int work = xcd * 63 + idx;
    const int head = work / 42;
    const int w2 = work - head * 42;
    const int qt = (w2 & 1) ? 21 + (w2 >> 1) : (w2 >> 1);
    const int nt = (qt < 21) ? 21 : 42;

    const int tid = threadIdx.x, lane = tid & 63, w = tid >> 6;
    const int pairI = w >> 1;        // j-half this wave computes
    const int qhalf = w & 1;         // q-row half of the 64-row job
    const int q31 = lane & 31, hi = lane >> 5;
    const size_t hOff = (size_t)head * ((size_t)L_SEQ * HD);
    const u16* Kh = kh + hOff;
    const u16* Vh = vt + hOff;
    const int qrow0 = qt * 64 + qhalf * 32;

    // Q B-fragments (n=q31, k = 16kk + 8hi .. +8): 8 k-steps
    s16x8 aq[8];
#pragma unroll
    for (int kk = 0; kk < 8; ++kk)
        aq[kk] = *(const s16x8*)&qh[hOff + (size_t)(qrow0 + q31) * HD + kk * 16 + hi * 8];

    // staging decomposition: ALL 256 threads stage the shared 32 KB tile.
    const int rh = tid >> 4, ck = tid & 15;
    const int rv = tid >> 3, cv = tid & 7;
    const int koff = 8 * (ck ^ rh);
    const int voff = 8 * (cv ^ (rv & 7));

#define STAGE_TILE(TG, BUF)                                                       \
    {                                                                             \
        char* dst = lsm[BUF];                                                     \
        _Pragma("unroll")                                                         \
        for (int i = 0; i < 4; ++i) {                                             \
            const u16* src = Kh + (size_t)((TG) * 64 + i * 16 + rh) * HD + koff;  \
            __builtin_amdgcn_global_load_lds(                                     \
                (const __attribute__((address_space(1))) u32*)src,                \
                (__attribute__((address_space(3))) u32*)(dst + i * 4096 + tid * 16), 16, 0, 0); \
        }                                                                         \
        _Pragma("unroll")                                                         \
        for (int i = 0; i < 4; ++i) {                                             \
            const u16* src = Vh + (size_t)(i * 32 + rv) * L_SEQ + (TG) * 64 + voff; \
            __builtin_amdgcn_global_load_lds(                                     \
                (const __attribute__((address_space(1))) u32*)src,                \
                (__attribute__((address_space(3))) u32*)(dst + 16384 + i * 4096 + tid * 16), 16, 0, 0); \
        }                                                                         \
    }

    f32x16 acc[4] = {};
    float mrun = -1e30f, lrun = 0.f;
    const float sc2 = 0.12751739646917983f;  // 1/sqrt(128) * log2(e)
    const int krow = pairI * 32 + q31;

    STAGE_TILE(0, 0);
    __syncthreads();
    for (int t = 0; t < nt; ++t) {
        if (t < nt - 1) STAGE_TILE(t + 1, (t + 1) & 1);
        const char* slot = lsm[t & 1];

        // ---- S^T = K Q^T, two independent accumulator chains (depth 4 each)
        f32x16 sv0 = {}, sv1 = {};
        __builtin_amdgcn_s_setprio(1);
#pragma unroll
        for (int kk = 0; kk < 4; ++kk) {
            int off0 = krow * 256 + ((kk * 32 + hi * 16) ^ ((q31 & 15) << 4));
            int off1 = krow * 256 + (((kk + 4) * 32 + hi * 16) ^ ((q31 & 15) << 4));
            s16x8 kf0 = *(const s16x8*)(slot + off0);
            s16x8 kf1 = *(const s16x8*)(slot + off1);
            sv0 = __builtin_amdgcn_mfma_f32_32x32x16_bf16(kf0, aq[kk], sv0, 0, 0, 0);
            sv1 = __builtin_amdgcn_mfma_f32_32x32x16_bf16(kf1, aq[kk + 4], sv1, 0, 0, 0);
        }
        __builtin_amdgcn_s_setprio(0);
        f32x16 sv;
#pragma unroll
        for (int e = 0; e < 16; ++e) sv[e] = sv0[e] + sv1[e];

        // ---- row max: depth-4 pairwise tree + one cross-half shuffle
        float m8[8];
#pragma unroll
        for (int e = 0; e < 8; ++e) m8[e] = fmaxf(sv[e], sv[e + 8]);
        float m4a = fmaxf(m8[0], m8[1]), m4b = fmaxf(m8[2], m8[3]);
        float m4c = fmaxf(m8[4], m8[5]), m4d = fmaxf(m8[6], m8[7]);
        float mx = fmaxf(fmaxf(m4a, m4b), fmaxf(m4c, m4d));
        mx = fmaxf(mx, __shfl_xor(mx, 32, 64));
        mx *= sc2;
        const int resc = (mx - mrun) > 11.5f;
        const float mm = resc ? mx : mrun;
        const float fac = resc ? __builtin_amdgcn_exp2f(mrun - mm) : 1.0f;
        mrun = mm;
#pragma unroll
        for (int e = 0; e < 16; ++e)
            sv[e] = __builtin_amdgcn_exp2f(sv[e] * sc2 - mm);
        float s8[8];
#pragma unroll
        for (int e = 0; e < 8; ++e) s8[e] = sv[e] + sv[e + 8];
        float s4a = s8[0] + s8[1], s4b = s8[2] + s8[3];
        float s4c = s8[4] + s8[5], s4d = s8[6] + s8[7];
        float sum = (s4a + s4b) + (s4c + s4d);
        sum += __shfl_xor(sum, 32, 64);
        lrun = lrun * fac + sum;
        if (__any(resc)) {
#pragma unroll
            for (int ds = 0; ds < 4; ++ds)
#pragma unroll
                for (int e = 0; e < 16; ++e) acc[ds][e] *= fac;
        }

        // ---- pack P -> 2 B-fragments in-register (cvt_pk + permlane32_swap)
        s16x8 pa[2];
#pragma unroll
        for (int hf = 0; hf < 2; ++hf) {
            u32 a0 = cvt_pk_bf16(sv[hf * 8 + 0], sv[hf * 8 + 1]);
            u32 a1 = cvt_pk_bf16(sv[hf * 8 + 2], sv[hf * 8 + 3]);
            u32 b0 = cvt_pk_bf16(sv[hf * 8 + 4], sv[hf * 8 + 5]);
            u32 b1 = cvt_pk_bf16(sv[hf * 8 + 6], sv[hf * 8 + 7]);
            i32x2 r0 = __builtin_amdgcn_permlane32_swap((int)a0, (int)b0, false, false);
            i32x2 r1 = __builtin_amdgcn_permlane32_swap((int)a1, (int)b1, false, false);
            u32x4 fw;
            fw.x = (u32)r0.x; fw.y = (u32)r1.x; fw.z = (u32)r0.y; fw.w = (u32)r1.y;
            pa[hf] = __builtin_bit_cast(s16x8, fw);
        }

        // ---- O^T += V^T P^T over this pair's j-half (2 k-steps of 16)
        __builtin_amdgcn_s_setprio(1);
#pragma unroll
        for (int jstep = 0; jstep < 2; ++jstep)
#pragma unroll
            for (int ds = 0; ds < 4; ++ds) {
                int off = 16384 + (ds * 32 + q31) * 128 +
                          ((pairI * 64 + jstep * 32 + hi * 16) ^ ((q31 & 7) << 4));
                s16x8 vf = *(const s16x8*)(slot + off);
                acc[ds] = __builtin_amdgcn_mfma_f32_32x32x16_bf16(vf, pa[jstep], acc[ds], 0, 0, 0);
            }
        __builtin_amdgcn_s_setprio(0);
        __syncthreads();                 // readers done + next stage drained
    }

    // ---- pair merge in LDS: waves 2,3 publish; waves 0,1 combine + output
    float2* mlb = (float2*)(lsm[1]);
    char* accb = lsm[0];
    if (w >= 2) {
        char* base = accb + qhalf * 16384 + lane * 256;
#pragma unroll
        for (int ds = 0; ds < 4; ++ds)
#pragma unroll
            for (int g = 0; g < 4; ++g) {
                f32x4 v4;
#pragma unroll
                for (int e = 0; e < 4; ++e) v4[e] = acc[ds][g * 4 + e];
                *(f32x4*)(base + (((ds * 4 + g) * 16) ^ ((lane & 15) << 4))) = v4;
            }
        if (hi == 0) {
            float2 t2; t2.x = mrun; t2.y = lrun;
            mlb[qhalf * 32 + q31] = t2;
        }
    }
    __syncthreads();
    if (w < 2) {
        float2 ml2 = mlb[qhalf * 32 + q31];
        float M = fmaxf(mrun, ml2.x);
        float wa = exp2f(mrun - M), wb = exp2f(ml2.x - M);
        lrun = lrun * wa + ml2.y * wb;
        const char* base = accb + qhalf * 16384 + lane * 256;
#pragma unroll
        for (int ds = 0; ds < 4; ++ds)
#pragma unroll
            for (int g = 0; g < 4; ++g) {
                f32x4 v4 = *(const f32x4*)(base + (((ds * 4 + g) * 16) ^ ((lane & 15) << 4)));
#pragma unroll
                for (int e = 0; e < 4; ++e) acc[ds][g * 4 + e] = acc[ds][g * 4 + e] * wa + v4[e] * wb;
            }
        const float inv = 1.0f / lrun;
        u16* orow = ob + (size_t)(qrow0 + q31) * DIM + head * HD;
#pragma unroll
        for (int ds = 0; ds < 4; ++ds)
#pragma unroll
            for (int g = 0; g < 4; ++g) {
                uint2 pk2;
                pk2.x = cvt_pk_bf16(acc[ds][g * 4 + 0] * inv, acc[ds][g * 4 + 1] * inv);
                pk2.y = cvt_pk_bf16(acc[ds][g * 4 + 2] * inv, acc[ds][g * 4 + 3] * inv);
                *(uint2*)(orow + ds * 32 + g * 8 + hi * 4) = pk2;
            }
    }
#undef STAGE_TILE
}

// ---------------------------------------------------------------- launcher
extern "C" void kernel_launch(void* const* d_in, const int* in_sizes, int n_in,
                              void* d_out, int out_size, void* d_ws, size_t ws_size,
                              hipStream_t stream) {
    const float* x     = (const float*)d_in[0];
    const float* freqs = (const float*)d_in[3];
    const float* Wq    = (const float*)d_in[4];
    const float* bq    = (const float*)d_in[5];
    const float* Wk    = (const float*)d_in[6];
    const float* bk    = (const float*)d_in[7];
    const float* Wv    = (const float*)d_in[8];
    const float* bv    = (const float*)d_in[9];
    const float* Wo    = (const float*)d_in[10];
    const float* bo    = (const float*)d_in[11];
    const float* gq    = (const float*)d_in[12];
    const float* gk    = (const float*)d_in[13];

    const size_t LD = (size_t)L_SEQ * DIM;   // elements
    u16* wt_all  = (u16*)d_ws;                         // 4 * DIM*DIM bf16
    u16* xb      = wt_all + (size_t)4 * DIM * DIM;     // L*DIM
    u16* pre_all = xb + LD;                            // 3 * L*DIM (q,k,v pre)
    u16* qh      = pre_all + 3 * LD;                   // [h][i][d]
    u16* kh2     = qh + LD;
    u16* vt      = kh2 + LD;
    u16* ob      = vt + LD;                            // attn out bf16 [i][c]

    k_prep<<<dim3(2016 + 2304), 256, 0, stream>>>(x, xb, Wq, Wk, Wv, Wo, wt_all);
    k_gemm<0><<<dim3(756), 256, 0, stream>>>(xb, wt_all, bq, bk, bv, pre_all);
    k_post<<<dim3(5376 + 1008), 256, 0, stream>>>(pre_all, gq, gk, freqs, qh, kh2, vt);
    k_attn<<<dim3(504), 256, 0, stream>>>(qh, kh2, vt, ob);
    k_gemm<1><<<dim3(252), 256, 0, stream>>>(ob, wt_all + (size_t)3 * DIM * DIM, bo, bo, bo, d_out);
}

// Round 20
// 153.418 us; speedup vs baseline: 1.0364x; 1.0098x over previous
//
#include <hip/hip_runtime.h>

#define L_SEQ 2688
#define DIM   1536
#define NH    12
#define HD    128
#define BLK_TOK 1344   // 3*H*W
#define HW_   448      // H*W
#define W_    28
#define NKIT  24       // DIM/64 K-iterations

typedef unsigned short u16;
typedef unsigned int   u32;
typedef __attribute__((ext_vector_type(4))) float f32x4;
typedef __attribute__((ext_vector_type(16))) float f32x16;
typedef __attribute__((ext_vector_type(8))) short s16x8;
typedef __attribute__((ext_vector_type(2))) int i32x2;
typedef __attribute__((ext_vector_type(4))) u32 u32x4;

__device__ __forceinline__ u16 f2b(float f) {
    u32 u = __builtin_bit_cast(u32, f);
    return (u16)((u + 0x7FFFu + ((u >> 16) & 1u)) >> 16);   // RNE
}
__device__ __forceinline__ float b2f(u16 b) {
    return __builtin_bit_cast(float, (u32)b << 16);
}
__device__ __forceinline__ u32 cvt_pk_bf16(float lo, float hi) {
    u32 r;
    asm("v_cvt_pk_bf16_f32 %0, %1, %2" : "=v"(r) : "v"(lo), "v"(hi));
    return r;
}

// -------------------- fused prep: x->bf16 (blocks 0..2015) ∥ W transpose
__global__ __launch_bounds__(256) void k_prep(const float* __restrict__ x,
                                              u16* __restrict__ xb,
                                              const float* __restrict__ w0,
                                              const float* __restrict__ w1,
                                              const float* __restrict__ w2,
                                              const float* __restrict__ w3,
                                              u16* __restrict__ wt_all) {
    __shared__ float t[64][65];
    const int bid = blockIdx.x;
    if (bid < 2016) {
        const int n4 = (int)((size_t)L_SEQ * DIM / 4);
        int i = bid * 256 + threadIdx.x;
        const int stride = 2016 * 256;
        for (; i < n4; i += stride) {
            float4 v = ((const float4*)x)[i];
            ushort4 o;
            o.x = f2b(v.x); o.y = f2b(v.y); o.z = f2b(v.z); o.w = f2b(v.w);
            ((ushort4*)xb)[i] = o;
        }
    } else {
        const int idx = bid - 2016;               // 0..2303
        const int z = idx / 576;
        const int rem = idx - z * 576;
        const int by = rem / 24, bx = rem - by * 24;
        const float* w = z == 0 ? w0 : z == 1 ? w1 : z == 2 ? w2 : w3;
        u16* wt = wt_all + (size_t)z * DIM * DIM;
        const int k0 = by * 64, n0 = bx * 64;
        const int c = threadIdx.x & 63, rg = threadIdx.x >> 6;
#pragma unroll
        for (int it = 0; it < 16; ++it) {
            int r = rg * 16 + it;
            t[r][c] = w[(size_t)(k0 + r) * DIM + n0 + c];
        }
        __syncthreads();
#pragma unroll
        for (int it = 0; it < 16; ++it) {
            int r = rg * 16 + it;
            wt[(size_t)(n0 + r) * DIM + k0 + c] = f2b(t[c][r]);
        }
    }
}

// ------------------------------------------------- GEMM v3: C = A*Bt^T + bias
// (R17 version — best measured)
template<int OUTF>
__global__ __launch_bounds__(256) void k_gemm(const u16* __restrict__ A,
                                              const u16* __restrict__ Bt_all,
                                              const float* __restrict__ b0,
                                              const float* __restrict__ b1,
                                              const float* __restrict__ b2,
                                              void* __restrict__ out_all) {
    // bijective XCD swizzle over flat worklist
    const int NW = OUTF ? 252 : 756;
    const int qc = NW >> 3, rq = NW & 7;
    const int xcd = blockIdx.x & 7, idx = blockIdx.x >> 3;
    const int work = (xcd < rq) ? xcd * (qc + 1) + idx
                                : rq * (qc + 1) + (xcd - rq) * qc + idx;
    int z, bm, bn;
    if (OUTF) { z = 0; bm = work / 12; bn = work - bm * 12; }
    else      { z = work / 252; int rem = work - z * 252; bm = rem / 12; bn = rem - bm * 12; }

    const u16* Bt = Bt_all + (size_t)z * DIM * DIM;
    const float* bias = z == 0 ? b0 : z == 1 ? b1 : b2;

    __shared__ u16 lbuf[2][2][8192];   // [dbuf][A/B][128 rows x 64 cols, granule-swizzled]
    const int tid = threadIdx.x, lane = tid & 63, wid = tid >> 6;
    const int wm = wid >> 1, wn = wid & 1;
    const int q31 = lane & 31, hi = lane >> 5;

    const int sr = tid >> 3, sc = tid & 7;
    const int scol = 8 * (sc ^ (sr & 7));
    const u16* aRow = A  + (size_t)(bm * 128 + sr) * DIM + scol;
    const u16* bRow = Bt + (size_t)(bn * 128 + sr) * DIM + scol;

#define GSTAGE(KT, BUF)                                                            \
    {                                                                              \
        _Pragma("unroll")                                                          \
        for (int i = 0; i < 4; ++i)                                                \
            __builtin_amdgcn_global_load_lds(                                      \
                (const __attribute__((address_space(1))) u32*)(aRow + (size_t)i * 32 * DIM + (KT) * 64), \
                (__attribute__((address_space(3))) u32*)((char*)&lbuf[BUF][0][0] + i * 4096 + tid * 16), \
                16, 0, 0);                                                         \
        _Pragma("unroll")                                                          \
        for (int i = 0; i < 4; ++i)                                                \
            __builtin_amdgcn_global_load_lds(                                      \
                (const __attribute__((address_space(1))) u32*)(bRow + (size_t)i * 32 * DIM + (KT) * 64), \
                (__attribute__((address_space(3))) u32*)((char*)&lbuf[BUF][1][0] + i * 4096 + tid * 16), \
                16, 0, 0);                                                         \
    }

    f32x16 acc[2][2] = {};

    GSTAGE(0, 0);
    __syncthreads();
    for (int kt = 0; kt < NKIT; ++kt) {
        if (kt < NKIT - 1) GSTAGE(kt + 1, (kt + 1) & 1);
        const char* bufA = (const char*)&lbuf[kt & 1][0][0];
        const char* bufB = (const char*)&lbuf[kt & 1][1][0];
        s16x8 af[2][4], bf[2][4];
#pragma unroll
        for (int f = 0; f < 2; ++f)
#pragma unroll
            for (int kk = 0; kk < 4; ++kk) {
                const int ra = wm * 64 + f * 32 + q31;
                const int rb = wn * 64 + f * 32 + q31;
                const int cg = kk * 2 + hi;
                af[f][kk] = *(const s16x8*)(bufA + ra * 128 + (((cg) ^ (q31 & 7)) << 4));
                bf[f][kk] = *(const s16x8*)(bufB + rb * 128 + (((cg) ^ (q31 & 7)) << 4));
            }
        __builtin_amdgcn_s_setprio(1);
#pragma unroll
        for (int kk = 0; kk < 4; ++kk)
#pragma unroll
            for (int fm = 0; fm < 2; ++fm)
#pragma unroll
                for (int fn = 0; fn < 2; ++fn)
                    acc[fm][fn] = __builtin_amdgcn_mfma_f32_32x32x16_bf16(af[fm][kk], bf[fn][kk], acc[fm][fn], 0, 0, 0);
        __builtin_amdgcn_s_setprio(0);
        __syncthreads();
    }

#pragma unroll
    for (int fn = 0; fn < 2; ++fn) {
        const int col = bn * 128 + wn * 64 + fn * 32 + q31;
        const float bv = bias[col];
#pragma unroll
        for (int fm = 0; fm < 2; ++fm) {
#pragma unroll
            for (int e = 0; e < 16; ++e) {
                const int row = bm * 128 + wm * 64 + fm * 32 + (e & 3) + 8 * (e >> 2) + 4 * hi;
                const float v = acc[fm][fn][e] + bv;
                if (OUTF)
                    ((float*)out_all)[(size_t)row * DIM + col] = v;
                else
                    ((u16*)out_all)[(size_t)z * L_SEQ * DIM + (size_t)row * DIM + col] = f2b(v);
            }
        }
    }
#undef GSTAGE
}

// --------- fused post: RMSNorm+RoPE (blocks 0..5375) ∥ V transpose (rest)
__global__ __launch_bounds__(256) void k_post(const u16* __restrict__ pre_all,
                                              const float* __restrict__ gq,
                                              const float* __restrict__ gk,
                                              const float* __restrict__ freqs,
                                              u16* __restrict__ qh,
                                              u16* __restrict__ kh,
                                              u16* __restrict__ vt) {
    __shared__ float sred[4];
    __shared__ u16 tt[64][68];
    const int bid = blockIdx.x;
    const int t = threadIdx.x;
    if (bid < 5376) {
        const int which = bid & 1;
        const int i = bid >> 1;
        const u16* pre = pre_all + (size_t)which * L_SEQ * DIM;
        const float* g = which ? gk : gq;
        u16* outh = which ? kh : qh;
        const u32* prow = (const u32*)(pre + (size_t)i * DIM);

        float re[3], im[3];
        float ss = 0.f;
#pragma unroll
        for (int a = 0; a < 3; ++a) {
            u32 p = prow[t + a * 256];
            float x = b2f((u16)(p & 0xFFFFu)), y = b2f((u16)(p >> 16));
            re[a] = x; im[a] = y;
            ss += x * x + y * y;
        }
#pragma unroll
        for (int o = 32; o > 0; o >>= 1) ss += __shfl_down(ss, o, 64);
        if ((t & 63) == 0) sred[t >> 6] = ss;
        __syncthreads();
        float rms = rsqrtf((sred[0] + sred[1] + sred[2] + sred[3]) * (1.0f / DIM) + 1e-6f);

        const int f = i / HW_;
        const int rem = i - f * HW_;
        const int hp = rem / W_;
        const int wp = rem - hp * W_;
#pragma unroll
        for (int a = 0; a < 3; ++a) {
            int j = t + a * 256;
            int h = j >> 6, pj = j & 63;
            float2 gg = ((const float2*)g)[j];
            float x = re[a] * rms * gg.x;
            float y = im[a] * rms * gg.y;
            int ridx = pj < 22 ? f : (pj < 43 ? hp : wp);
            float2 cs = ((const float2*)freqs)[ridx * 64 + pj];
            float ore = x * cs.x - y * cs.y;
            float oim = x * cs.y + y * cs.x;
            u32 o = (u32)f2b(ore) | ((u32)f2b(oim) << 16);
            ((u32*)outh)[(size_t)h * (L_SEQ * 64) + (size_t)i * 64 + pj] = o;
        }
    } else {
        const int idx = bid - 5376;               // 0..1007
        const int h = idx / 84;
        const int rem = idx - h * 84;
        const int d0 = (rem / 42) * 64, i0 = (rem % 42) * 64;
        const u16* vpre = pre_all + (size_t)2 * L_SEQ * DIM;
        const int c = t & 63, rg = t >> 6;
#pragma unroll
        for (int it = 0; it < 16; ++it) {
            int r = rg * 16 + it;
            tt[r][c] = vpre[(size_t)(i0 + r) * DIM + h * HD + d0 + c];
        }
        __syncthreads();
#pragma unroll
        for (int it = 0; it < 16; ++it) {
            int r = rg * 16 + it;  // d index
            vt[(size_t)h * (HD * L_SEQ) + (size_t)(d0 + r) * L_SEQ + i0 + c] = tt[c][r];
        }
    }
}

// ----------------------------------------------------- flash attention v20
// v17 + V^T tile re-laid as 64 x 256B row-pairs (r=d>>1, o=(d&1)*128+jbyte)
// with 4-bit XOR swizzle (o ^= (r&15)<<4) -> PV fragment reads go 4-way ->
// 2-way (free) bank conflicts. Staging dst stays linear (gload_lds legal);
// only per-lane source addressing changes. Everything else identical.
__global__ __launch_bounds__(256, 2) void k_attn(const u16* __restrict__ qh,
                                                 const u16* __restrict__ kh,
                                                 const u16* __restrict__ vt,
                                                 u16* __restrict__ ob) {
    __shared__ char lsm[2][32768];   // dbuf slots: [0,16K) K[64][128] swz, [16K,32K) V^T row-pair swz

    // bijective XCD swizzle: 504 = 8*63; long/short interleaved within head
    const int flat = blockIdx.x;
    const int xcd = flat & 7, idx = flat >> 3;
    const int work = xcd * 63 + idx;
    const int head = work / 42;
    const int w2 = work - head * 42;
    const int qt = (w2 & 1) ? 21 + (w2 >> 1) : (w2 >> 1);
    const int nt = (qt < 21) ? 21 : 42;

    const int tid = threadIdx.x, lane = tid & 63, w = tid >> 6;
    const int pairI = w >> 1;        // j-half this wave computes
    const int qhalf = w & 1;         // q-row half of the 64-row job
    const int q31 = lane & 31, hi = lane >> 5;
    const size_t hOff = (size_t)head * ((size_t)L_SEQ * HD);
    const u16* Kh = kh + hOff;
    const u16* Vh = vt + hOff;
    const int qrow0 = qt * 64 + qhalf * 32;

    // Q B-fragments (n=q31, k = 16kk + 8hi .. +8): 8 k-steps
    s16x8 aq[8];
#pragma unroll
    for (int kk = 0; kk < 8; ++kk)
        aq[kk] = *(const s16x8*)&qh[hOff + (size_t)(qrow0 + q31) * HD + kk * 16 + hi * 8];

    // staging decomposition: ALL 256 threads stage the shared 32 KB tile.
    // K: granule G=i*256+tid -> row i*16+(tid>>4), slot tid&15, src col 8*(slot^row15)
    const int rh = tid >> 4, ck = tid & 15;
    const int koff = 8 * (ck ^ rh);
    // V: granule G=i*256+tid -> row-pair r=i*16+(tid>>4), slot s=tid&15;
    //    orig slot so=s^(r&15) -> d = i*32 + 2*(tid>>4) + (so>>3), jgran = so&7
    const int soV = ck ^ rh;                       // r&15 == tid>>4 (i*16 ≡ 0 mod 16)
    const int vdrow = 2 * rh + (soV >> 3);         // + i*32 per issue
    const int vjoff = 8 * (soV & 7);               // element offset

#define STAGE_TILE(TG, BUF)                                                       \
    {                                                                             \
        char* dst = lsm[BUF];                                                     \
        _Pragma("unroll")                                                         \
        for (int i = 0; i < 4; ++i) {                                             \
            const u16* src = Kh + (size_t)((TG) * 64 + i * 16 + rh) * HD + koff;  \
            __builtin_amdgcn_global_load_lds(                                     \
                (const __attribute__((address_space(1))) u32*)src,                \
                (__attribute__((address_space(3))) u32*)(dst + i * 4096 + tid * 16), 16, 0, 0); \
        }                                                                         \
        _Pragma("unroll")                                                         \
        for (int i = 0; i < 4; ++i) {                                             \
            const u16* src = Vh + (size_t)(i * 32 + vdrow) * L_SEQ + (TG) * 64 + vjoff; \
            __builtin_amdgcn_global_load_lds(                                     \
                (const __attribute__((address_space(1))) u32*)src,                \
                (__attribute__((address_space(3))) u32*)(dst + 16384 + i * 4096 + tid * 16), 16, 0, 0); \
        }                                                                         \
    }

    f32x16 acc[4] = {};
    float mrun = -1e30f, lrun = 0.f;
    const float sc2 = 0.12751739646917983f;  // 1/sqrt(128) * log2(e)
    const int krow = pairI * 32 + q31;
    const int jb0 = pairI * 64 + hi * 16;    // byte offset of j-range in 128B half-row

    STAGE_TILE(0, 0);
    __syncthreads();
    for (int t = 0; t < nt; ++t) {
        if (t < nt - 1) STAGE_TILE(t + 1, (t + 1) & 1);
        const char* slot = lsm[t & 1];

        // ---- S^T = K Q^T, two independent accumulator chains (depth 4 each)
        f32x16 sv0 = {}, sv1 = {};
        __builtin_amdgcn_s_setprio(1);
#pragma unroll
        for (int kk = 0; kk < 4; ++kk) {
            int off0 = krow * 256 + ((kk * 32 + hi * 16) ^ ((q31 & 15) << 4));
            int off1 = krow * 256 + (((kk + 4) * 32 + hi * 16) ^ ((q31 & 15) << 4));
            s16x8 kf0 = *(const s16x8*)(slot + off0);
            s16x8 kf1 = *(const s16x8*)(slot + off1);
            sv0 = __builtin_amdgcn_mfma_f32_32x32x16_bf16(kf0, aq[kk], sv0, 0, 0, 0);
            sv1 = __builtin_amdgcn_mfma_f32_32x32x16_bf16(kf1, aq[kk + 4], sv1, 0, 0, 0);
        }
        __builtin_amdgcn_s_setprio(0);
        f32x16 sv;
#pragma unroll
        for (int e = 0; e < 16; ++e) sv[e] = sv0[e] + sv1[e];

        // ---- row max: depth-4 pairwise tree + one cross-half shuffle
        float m8[8];
#pragma unroll
        for (int e = 0; e < 8; ++e) m8[e] = fmaxf(sv[e], sv[e + 8]);
        float m4a = fmaxf(m8[0], m8[1]), m4b = fmaxf(m8[2], m8[3]);
        float m4c = fmaxf(m8[4], m8[5]), m4d = fmaxf(m8[6], m8[7]);
        float mx = fmaxf(fmaxf(m4a, m4b), fmaxf(m4c, m4d));
        mx = fmaxf(mx, __shfl_xor(mx, 32, 64));
        mx *= sc2;
        const int resc = (mx - mrun) > 11.5f;
        const float mm = resc ? mx : mrun;
        const float fac = resc ? __builtin_amdgcn_exp2f(mrun - mm) : 1.0f;
        mrun = mm;
#pragma unroll
        for (int e = 0; e < 16; ++e)
            sv[e] = __builtin_amdgcn_exp2f(sv[e] * sc2 - mm);
        float s8[8];
#pragma unroll
        for (int e = 0; e < 8; ++e) s8[e] = sv[e] + sv[e + 8];
        float s4a = s8[0] + s8[1], s4b = s8[2] + s8[3];
        float s4c = s8[4] + s8[5], s4d = s8[6] + s8[7];
        float sum = (s4a + s4b) + (s4c + s4d);
        sum += __shfl_xor(sum, 32, 64);
        lrun = lrun * fac + sum;
        if (__any(resc)) {
#pragma unroll
            for (int ds = 0; ds < 4; ++ds)
#pragma unroll
                for (int e = 0; e < 16; ++e) acc[ds][e] *= fac;
        }

        // ---- pack P -> 2 B-fragments in-register (cvt_pk + permlane32_swap)
        s16x8 pa[2];
#pragma unroll
        for (int hf = 0; hf < 2; ++hf) {
            u32 a0 = cvt_pk_bf16(sv[hf * 8 + 0], sv[hf * 8 + 1]);
            u32 a1 = cvt_pk_bf16(sv[hf * 8 + 2], sv[hf * 8 + 3]);
            u32 b0 = cvt_pk_bf16(sv[hf * 8 + 4], sv[hf * 8 + 5]);
            u32 b1 = cvt_pk_bf16(sv[hf * 8 + 6], sv[hf * 8 + 7]);
            i32x2 r0 = __builtin_amdgcn_permlane32_swap((int)a0, (int)b0, false, false);
            i32x2 r1 = __builtin_amdgcn_permlane32_swap((int)a1, (int)b1, false, false);
            u32x4 fw;
            fw.x = (u32)r0.x; fw.y = (u32)r1.x; fw.z = (u32)r0.y; fw.w = (u32)r1.y;
            pa[hf] = __builtin_bit_cast(s16x8, fw);
        }

        // ---- O^T += V^T P^T over this pair's j-half (2 k-steps of 16)
        // V read: d = ds*32+q31 -> r=d>>1, o=(d&1)*128 + jb, addr = r*256 + (o ^ ((r&15)<<4))
        __builtin_amdgcn_s_setprio(1);
#pragma unroll
        for (int jstep = 0; jstep < 2; ++jstep) {
            const int jb = jb0 + jstep * 32;
#pragma unroll
            for (int ds = 0; ds < 4; ++ds) {
                const int rr = ds * 16 + (q31 >> 1);
                const int oo = ((q31 & 1) << 7) + jb;
                int off = 16384 + rr * 256 + (oo ^ ((rr & 15) << 4));
                s16x8 vf = *(const s16x8*)(slot + off);
                acc[ds] = __builtin_amdgcn_mfma_f32_32x32x16_bf16(vf, pa[jstep], acc[ds], 0, 0, 0);
            }
        }
        __builtin_amdgcn_s_setprio(0);
        __syncthreads();                 // readers done + next stage drained
    }

    // ---- pair merge in LDS: waves 2,3 publish; waves 0,1 combine + output
    float2* mlb = (float2*)(lsm[1]);
    char* accb = lsm[0];
    if (w >= 2) {
        char* base = accb + qhalf * 16384 + lane * 256;
#pragma unroll
        for (int ds = 0; ds < 4; ++ds)
#pragma unroll
            for (int g = 0; g < 4; ++g) {
                f32x4 v4;
#pragma unroll
                for (int e = 0; e < 4; ++e) v4[e] = acc[ds][g * 4 + e];
                *(f32x4*)(base + (((ds * 4 + g) * 16) ^ ((lane & 15) << 4))) = v4;
            }
        if (hi == 0) {
            float2 t2; t2.x = mrun; t2.y = lrun;
            mlb[qhalf * 32 + q31] = t2;
        }
    }
    __syncthreads();
    if (w < 2) {
        float2 ml2 = mlb[qhalf * 32 + q31];
        float M = fmaxf(mrun, ml2.x);
        float wa = exp2f(mrun - M), wb = exp2f(ml2.x - M);
        lrun = lrun * wa + ml2.y * wb;
        const char* base = accb + qhalf * 16384 + lane * 256;
#pragma unroll
        for (int ds = 0; ds < 4; ++ds)
#pragma unroll
            for (int g = 0; g < 4; ++g) {
                f32x4 v4 = *(const f32x4*)(base + (((ds * 4 + g) * 16) ^ ((lane & 15) << 4)));
#pragma unroll
                for (int e = 0; e < 4; ++e) acc[ds][g * 4 + e] = acc[ds][g * 4 + e] * wa + v4[e] * wb;
            }
        const float inv = 1.0f / lrun;
        u16* orow = ob + (size_t)(qrow0 + q31) * DIM + head * HD;
#pragma unroll
        for (int ds = 0; ds < 4; ++ds)
#pragma unroll
            for (int g = 0; g < 4; ++g) {
                uint2 pk2;
                pk2.x = cvt_pk_bf16(acc[ds][g * 4 + 0] * inv, acc[ds][g * 4 + 1] * inv);
                pk2.y = cvt_pk_bf16(acc[ds][g * 4 + 2] * inv, acc[ds][g * 4 + 3] * inv);
                *(uint2*)(orow + ds * 32 + g * 8 + hi * 4) = pk2;
            }
    }
#undef STAGE_TILE
}

// ---------------------------------------------------------------- launcher
extern "C" void kernel_launch(void* const* d_in, const int* in_sizes, int n_in,
                              void* d_out, int out_size, void* d_ws, size_t ws_size,
                              hipStream_t stream) {
    const float* x     = (const float*)d_in[0];
    const float* freqs = (const float*)d_in[3];
    const float* Wq    = (const float*)d_in[4];
    const float* bq    = (const float*)d_in[5];
    const float* Wk    = (const float*)d_in[6];
    const float* bk    = (const float*)d_in[7];
    const float* Wv    = (const float*)d_in[8];
    const float* bv    = (const float*)d_in[9];
    const float* Wo    = (const float*)d_in[10];
    const float* bo    = (const float*)d_in[11];
    const float* gq    = (const float*)d_in[12];
    const float* gk    = (const float*)d_in[13];

    const size_t LD = (size_t)L_SEQ * DIM;   // elements
    u16* wt_all  = (u16*)d_ws;                         // 4 * DIM*DIM bf16
    u16* xb      = wt_all + (size_t)4 * DIM * DIM;     // L*DIM
    u16* pre_all = xb + LD;                            // 3 * L*DIM (q,k,v pre)
    u16* qh      = pre_all + 3 * LD;                   // [h][i][d]
    u16* kh2     = qh + LD;
    u16* vt      = kh2 + LD;
    u16* ob      = vt + LD;                            // attn out bf16 [i][c]

    k_prep<<<dim3(2016 + 2304), 256, 0, stream>>>(x, xb, Wq, Wk, Wv, Wo, wt_all);
    k_gemm<0><<<dim3(756), 256, 0, stream>>>(xb, wt_all, bq, bk, bv, pre_all);
    k_post<<<dim3(5376 + 1008), 256, 0, stream>>>(pre_all, gq, gk, freqs, qh, kh2, vt);
    k_attn<<<dim3(504), 256, 0, stream>>>(qh, kh2, vt, ob);
    k_gemm<1><<<dim3(252), 256, 0, stream>>>(ob, wt_all + (size_t)3 * DIM * DIM, bo, bo, bo, d_out);
}